// Round 5
// baseline (191.040 us; speedup 1.0000x reference)
//
#include <hip/hip_runtime.h>

// ---------------------------------------------------------------------------
// QuantizedShaper: B=256, L=8192, DIM=256, NPAT=64, HIST=32, WIN=8, T=1024.
//
// R17: row-duplicated 4-patterns-per-lane scan -- ZERO cross-row ops.
// Evidence R12-R16: one 6-hop cross-lane reduce chain ~ 250 cyc/step; the
// marginal 2nd chain (R13) cost 225 => ~37 cyc/hop. Row-confined DPP stages
// are the cheap known-good part (R12); the cross-row hops (permlane_swap /
// swizzle / readlane) are the prime suspects. R17 removes them:
//   lane l, slot s holds pattern 4*(l&15)+s, DUPLICATED across all 4 rows.
//   global max = fold4 (depth 2) + xor1/xor2/half_mirror/mirror (4 row-DPP
//   hops) -> g in every lane. No permlane, no LDS, no readlane, no VCC.
// Per-slot e via R16's validated float-mask trick (R16==R14 proved this
// bookkeeping free); C/v/pA/bm duplicated across rows (consistent).
// U via 8-deep float4 register ring (prefetch 6+ steps ahead, static idx).
// Winner extraction + epilogue = R15's validated byte path (16-lane
// ballots & 0xFFFF). Decisions bitwise-identical per pattern to R12-R16:
// same U, same max of same 64 values (fmax exact), same vA=U-C / vB=vA-1
// semantics via v' = pA - e, pA = U[i+2] - C (R16's validated recurrence).
// ---------------------------------------------------------------------------

constexpr int Bb = 256, Ll = 8192, DIMc = 256, NPAT = 64, HIST = 32, WINc = 8;
constexpr int Tt = Ll / WINc;   // 1024
constexpr int TC = 32;          // t-chunk
constexpr int NC = Tt / TC;     // 32 chunks
constexpr float CINV = 1.0f / 64.0f;

#define DPP_STAGE(m, ctrl, rmask)                                              \
  (m) = fmaxf((m), __int_as_float(__builtin_amdgcn_update_dpp(                 \
            __float_as_int(m), __float_as_int(m), (ctrl), (rmask), 0xF, false)))

#define DPP_ADDF(s, ctrl, rmask)                                               \
  do {                                                                         \
    int _si = __float_as_int(s);                                               \
    int _ti = __builtin_amdgcn_update_dpp(_si, _si, (ctrl), (rmask), 0xF, false); \
    (s) += __int_as_float(_ti);                                                \
  } while (0)

#if defined(__has_builtin)
#if __has_builtin(__builtin_amdgcn_fmed3f)
#define HAVE_MED3 1
#endif
#endif

__device__ __forceinline__ float clamp01(float t) {
#if defined(HAVE_MED3)
  return __builtin_amdgcn_fmed3f(t, 0.0f, 1.0f);
#else
  return fminf(fmaxf(t, 0.0f), 1.0f);
#endif
}

// one block per pattern p: W2[p,0..31] + bias2[p]
__global__ __launch_bounds__(256) void precompute_kernel(
    const float* __restrict__ conv_w, const float* __restrict__ conv_b,
    const float* __restrict__ keys_w, float* __restrict__ wsf) {
  __shared__ float part[8][32];
  __shared__ float bred[4];
  const int p = blockIdx.x;
  const int t = threadIdx.x;
  const int h = t & 31, g = t >> 5;
  const float* kwp = keys_w + (size_t)p * DIMc;

  float acc = 0.f;
#pragma unroll
  for (int dd = 0; dd < 32; ++dd) {
    int d = g * 32 + dd;
    acc = fmaf(kwp[d], conv_w[d * HIST + h], acc);
  }
  part[g][h] = acc;

  float bp = kwp[t] * conv_b[t];
#pragma unroll
  for (int off = 32; off; off >>= 1) bp += __shfl_down(bp, off);
  if ((t & 63) == 0) bred[t >> 6] = bp;
  __syncthreads();

  if (t < 32) {
    float s = 0.f;
#pragma unroll
    for (int gg = 0; gg < 8; ++gg) s += part[gg][t];
    wsf[(t >> 2) * (NPAT * 4) + p * 4 + (t & 3)] = s;  // float4-friendly
  } else if (t == 32) {
    wsf[NPAT * HIST + p] = (bred[0] + bred[1]) + (bred[2] + bred[3]);
  }
}

__global__ __launch_bounds__(256) void shaper_kernel(
    const float* __restrict__ x, const float* __restrict__ avg_init,
    const float* __restrict__ shapes_w, const float* __restrict__ wsf,
    float* __restrict__ out) {
  __shared__ __align__(16) float xpad[HIST - 1 + Ll + 1];
  __shared__ __align__(16) float scb[2][TC * NPAT];
  __shared__ unsigned int bmw[2][4][16];     // per-chunk win masks, dbuf
  __shared__ unsigned char idx8[Tt];         // winner pattern per step
  __shared__ float shp[WINc * NPAT];

  const int b    = blockIdx.x;
  const int tid  = threadIdx.x;
  const int wid  = tid >> 6;
  const int lane = tid & 63;
  const float* xrow = x + (size_t)b * Ll;

  // ---- stage x (left-padded) + shapes into LDS ----
  if (tid < HIST - 1) xpad[tid] = 0.f;
  {
    const float4* xv4 = (const float4*)xrow;
#pragma unroll
    for (int k = 0; k < 8; ++k) {
      int i4 = k * 256 + tid;
      float4 v = xv4[i4];
      float* dst = xpad + HIST - 1 + i4 * 4;
      dst[0] = v.x; dst[1] = v.y; dst[2] = v.z; dst[3] = v.w;
    }
  }
  for (int i = tid; i < WINc * NPAT; i += 256) shp[i] = shapes_w[i];

  // ---- av0 via DPP-sum butterfly (all waves; validated R5/R8/R10) ----
  float av0;
  {
    float s = avg_init[(size_t)b * NPAT + lane];
    float t = s;
    DPP_ADDF(t, 0xB1, 0xF);
    DPP_ADDF(t, 0x4E, 0xF);
    DPP_ADDF(t, 0x141, 0xF);
    DPP_ADDF(t, 0x140, 0xF);
    DPP_ADDF(t, 0x142, 0xA);
    DPP_ADDF(t, 0x143, 0xC);   // lane63 = total
    float tot = __int_as_float(__builtin_amdgcn_readlane(__float_as_int(t), 63));
    av0 = s - tot * CINV;
  }

  // ---- per-role setup ----
  float4 w2v[8];
  float  b2 = 0.f;
  if (wid > 0) {
    const float4* w2g = (const float4*)wsf;
#pragma unroll
    for (int h4 = 0; h4 < 8; ++h4) w2v[h4] = w2g[h4 * 64 + lane];
    b2 = wsf[NPAT * HIST + lane];
  }
  __syncthreads();

  // fill chunk c: sb[t][p] = (relu6(score) - av0[p]) + tglob/64  (== U_t[p])
  // (bitwise-identical to R12-R16; do not touch the fma order)
  auto fill = [&](int c, float* __restrict__ sb) {
    int base = c * TC;
    for (int tl = wid - 1; tl < TC; tl += 3) {
      int t = base + tl;
      const float4* xw = (const float4*)(xpad + t * WINc);  // 32B-aligned
      float acc = b2;
#pragma unroll
      for (int h4 = 0; h4 < 8; ++h4) {
        float4 xv = xw[h4];
        float4 wv = w2v[h4];
        acc = fmaf(xv.x, wv.x, acc);
        acc = fmaf(xv.y, wv.y, acc);
        acc = fmaf(xv.z, wv.z, acc);
        acc = fmaf(xv.w, wv.w, acc);
      }
      float sc = fminf(fmaxf(acc, 0.f), 6.f);
      sb[tl * NPAT + lane] = (sc - av0) + (float)t * CINV;
    }
  };

  // ---- scan state (wave 0): per-slot win counts, across chunks ----
  float C0 = 0.f, C1 = 0.f, C2 = 0.f, C3 = 0.f;
  constexpr float SC75 = 37778931862957161709568.0f;  // 2^75

  // Row-duplicated 4-per-lane scan: every 16-lane row holds all 64 patterns.
  auto scan_chunk = [&](const float* __restrict__ sb, int cidx) {
    const float4* sv = (const float4*)sb + (lane & 15);  // +16 float4 / step
    float4 R[8];
#pragma unroll
    for (int k = 0; k < 8; ++k) R[k] = sv[k * 16];
    float bmA0 = 0.f, bmA1 = 0.f, bmA2 = 0.f, bmA3 = 0.f;
    float bmB0 = 0.f, bmB1 = 0.f, bmB2 = 0.f, bmB3 = 0.f;
    float v0 = R[0].x - C0, v1 = R[0].y - C1;
    float v2 = R[0].z - C2, v3 = R[0].w - C3;
    float pA0 = R[1].x - C0, pA1 = R[1].y - C1;
    float pA2 = R[1].z - C2, pA3 = R[1].w - C3;
#pragma unroll
    for (int i = 0; i < TC; ++i) {
      if (i + 8 < TC) R[i & 7] = sv[(i + 8) * 16];  // ring prefetch (6+ steps)
      float g = fmaxf(fmaxf(v0, v1), fmaxf(v2, v3));
      DPP_STAGE(g, 0xB1, 0xF);   // xor1  (quad)
      DPP_STAGE(g, 0x4E, 0xF);   // xor2  (quad)
      DPP_STAGE(g, 0x141, 0xF);  // row_half_mirror -> 8-group max
      DPP_STAGE(g, 0x140, 0xF);  // row_mirror -> 16-lane (=global) max
      float d0 = g - v0, d1 = g - v1, d2 = g - v2, d3 = g - v3;
      float e0 = clamp01(__builtin_fmaf(d0 * SC75, -SC75, 1.0f));
      float e1 = clamp01(__builtin_fmaf(d1 * SC75, -SC75, 1.0f));
      float e2 = clamp01(__builtin_fmaf(d2 * SC75, -SC75, 1.0f));
      float e3 = clamp01(__builtin_fmaf(d3 * SC75, -SC75, 1.0f));
      C0 += e0; C1 += e1; C2 += e2; C3 += e3;
      if (i < 16) {
        float w = (float)(1u << i);
        bmA0 = __builtin_fmaf(e0, w, bmA0);
        bmA1 = __builtin_fmaf(e1, w, bmA1);
        bmA2 = __builtin_fmaf(e2, w, bmA2);
        bmA3 = __builtin_fmaf(e3, w, bmA3);
      } else {
        float w = (float)(1u << (i - 16));
        bmB0 = __builtin_fmaf(e0, w, bmB0);
        bmB1 = __builtin_fmaf(e1, w, bmB1);
        bmB2 = __builtin_fmaf(e2, w, bmB2);
        bmB3 = __builtin_fmaf(e3, w, bmB3);
      }
      if (i + 1 < TC) {
        v0 = pA0 - e0;  v1 = pA1 - e1;
        v2 = pA2 - e2;  v3 = pA3 - e3;
        if (i + 2 < TC) {
          float4 R2 = R[(i + 2) & 7];
          pA0 = R2.x - C0; pA1 = R2.y - C1;
          pA2 = R2.z - C2; pA3 = R2.w - C3;
        }
      }
    }
    if (lane < 16) {
      bmw[cidx & 1][0][lane] = (unsigned int)bmA0 | ((unsigned int)bmB0 << 16);
      bmw[cidx & 1][1][lane] = (unsigned int)bmA1 | ((unsigned int)bmB1 << 16);
      bmw[cidx & 1][2][lane] = (unsigned int)bmA2 | ((unsigned int)bmB2 << 16);
      bmw[cidx & 1][3][lane] = (unsigned int)bmA3 | ((unsigned int)bmB3 << 16);
    }
  };

  // batched winner extraction for chunk cc, split across fill waves 1-3
  // (R15-validated structure; pattern = 4*lane16 + slot)
  auto extract = [&](int cc) {
    unsigned int m0 = bmw[cc & 1][0][lane & 15];
    unsigned int m1 = bmw[cc & 1][1][lane & 15];
    unsigned int m2 = bmw[cc & 1][2][lane & 15];
    unsigned int m3 = bmw[cc & 1][3][lane & 15];
    for (int i = wid - 1; i < TC; i += 3) {
      unsigned long long k0 = __ballot(((m0 >> i) & 1u) != 0u) & 0xFFFFull;
      unsigned long long k1 = __ballot(((m1 >> i) & 1u) != 0u) & 0xFFFFull;
      unsigned long long k2 = __ballot(((m2 >> i) & 1u) != 0u) & 0xFFFFull;
      unsigned long long k3 = __ballot(((m3 >> i) & 1u) != 0u) & 0xFFFFull;
      int w = 0;
      if (k0) w = 4 * (int)(__ffsll(k0) - 1) + 0;
      if (k1) w = 4 * (int)(__ffsll(k1) - 1) + 1;
      if (k2) w = 4 * (int)(__ffsll(k2) - 1) + 2;
      if (k3) w = 4 * (int)(__ffsll(k3) - 1) + 3;
      if (lane == 0) idx8[cc * TC + i] = (unsigned char)w;
    }
  };

  // ---- pipeline: wave0 scans chunk c; waves1-3 fill chunk c+1 and
  //      extract winners of chunk c-1 ----
  if (wid > 0) fill(0, scb[0]);
  __syncthreads();

  for (int c = 0; c < NC; ++c) {
    if (wid == 0) {
      scan_chunk(scb[c & 1], c);
    } else {
      if (c + 1 < NC) fill(c + 1, scb[(c + 1) & 1]);
      if (c >= 1) extract(c - 1);
    }
    __syncthreads();
  }
  if (wid > 0) extract(NC - 1);
  __syncthreads();

  // ---- epilogue: out[b,l] = relu(shapes[l&7, idx[l>>3]] - x[b,l]) ----
  float4* outv = (float4*)(out + (size_t)b * Ll);
#pragma unroll
  for (int k = 0; k < 8; ++k) {
    int i4 = k * 256 + tid;
    int l0 = i4 * 4;
    int t  = l0 >> 3;
    int w0 = l0 & 7;
    int p  = (int)idx8[t];
    float4 o;
    o.x = fmaxf(shp[(w0 + 0) * NPAT + p] - xpad[HIST - 1 + l0 + 0], 0.f);
    o.y = fmaxf(shp[(w0 + 1) * NPAT + p] - xpad[HIST - 1 + l0 + 1], 0.f);
    o.z = fmaxf(shp[(w0 + 2) * NPAT + p] - xpad[HIST - 1 + l0 + 2], 0.f);
    o.w = fmaxf(shp[(w0 + 3) * NPAT + p] - xpad[HIST - 1 + l0 + 3], 0.f);
    outv[i4] = o;
  }
}

extern "C" void kernel_launch(void* const* d_in, const int* in_sizes, int n_in,
                              void* d_out, int out_size, void* d_ws, size_t ws_size,
                              hipStream_t stream) {
  const float* x        = (const float*)d_in[0];
  const float* avg_init = (const float*)d_in[1];
  const float* conv_w   = (const float*)d_in[2];
  const float* conv_b   = (const float*)d_in[3];
  const float* keys_w   = (const float*)d_in[4];
  const float* shapes_w = (const float*)d_in[5];
  float* wsf = (float*)d_ws;

  precompute_kernel<<<NPAT, 256, 0, stream>>>(conv_w, conv_b, keys_w, wsf);
  shaper_kernel<<<Bb, 256, 0, stream>>>(x, avg_init, shapes_w, wsf,
                                        (float*)d_out);
}

// Round 6
// 170.928 us; speedup vs baseline: 1.1177x; 1.1177x over previous
//
#include <hip/hip_runtime.h>

// ---------------------------------------------------------------------------
// QuantizedShaper: B=256, L=8192, DIM=256, NPAT=64, HIST=32, WIN=8, T=1024.
//
// R18: per-role top-level code split. Evidence R12-R17: step-body style and
// chain-hops DON'T matter (R12~R14~R16 ~252-265 cyc/step; R15/R17 ~307 with
// bigger bodies; R13 2x body = 2x time). The shared ~250cyc floor is per-step
// LDS round-trips from register pressure: U[32] and w2v[32] (live across the
// chunk loop for fill) can't both fit at VGPR=68, so the compiler re-reads
// U from LDS inside every step (~120-240 cyc exposed, queued behind fill's
// LDS bursts). Fix: wave0 and waves1-3 take DISJOINT top-level branches with
// matched barrier sequences (35 each) -> U and w2v are never co-live -> the
// allocator overlaps them and U stays register-resident (loaded once per
// chunk as 32 pipelined ds_read_b32).
// Scan body = R16's validated float-mask step (bitwise-identical decisions:
// v'=pA-e, pA=U[i+2]-C, e=clamp01(fmaf(d*2^75,-2^75,1)), C integer-exact).
// Extraction = R15's validated byte path, split across fill waves.
// ---------------------------------------------------------------------------

constexpr int Bb = 256, Ll = 8192, DIMc = 256, NPAT = 64, HIST = 32, WINc = 8;
constexpr int Tt = Ll / WINc;   // 1024
constexpr int TC = 32;          // t-chunk
constexpr int NC = Tt / TC;     // 32 chunks
constexpr float CINV = 1.0f / 64.0f;

#define DPP_STAGE(m, ctrl, rmask)                                              \
  (m) = fmaxf((m), __int_as_float(__builtin_amdgcn_update_dpp(                 \
            __float_as_int(m), __float_as_int(m), (ctrl), (rmask), 0xF, false)))

#define DPP_ADDF(s, ctrl, rmask)                                               \
  do {                                                                         \
    int _si = __float_as_int(s);                                               \
    int _ti = __builtin_amdgcn_update_dpp(_si, _si, (ctrl), (rmask), 0xF, false); \
    (s) += __int_as_float(_ti);                                                \
  } while (0)

#if defined(__has_builtin)
#if __has_builtin(__builtin_amdgcn_permlane16_swap)
#define HAVE_PL16 1
#endif
#if __has_builtin(__builtin_amdgcn_permlane32_swap)
#define HAVE_PL32 1
#endif
#if __has_builtin(__builtin_amdgcn_fmed3f)
#define HAVE_MED3 1
#endif
#endif

__device__ __forceinline__ float clamp01(float t) {
#if defined(HAVE_MED3)
  return __builtin_amdgcn_fmed3f(t, 0.0f, 1.0f);
#else
  return fminf(fmaxf(t, 0.0f), 1.0f);
#endif
}

// 64-lane max, result in ALL lanes, pure VALU. Validated R13/R14/R16.
__device__ __forceinline__ float wave_max64(float v, int lane) {
  float m = v;
  DPP_STAGE(m, 0xB1, 0xF);   // xor1
  DPP_STAGE(m, 0x4E, 0xF);   // xor2
  DPP_STAGE(m, 0x141, 0xF);  // row_half_mirror -> 8-group max
  DPP_STAGE(m, 0x140, 0xF);  // row_mirror -> 16-row max
#if defined(HAVE_PL16)
  {
    auto r = __builtin_amdgcn_permlane16_swap(__float_as_int(m),
                                              __float_as_int(m), false, false);
    m = fmaxf(__int_as_float(r[0]), __int_as_float(r[1]));  // 32-half max
  }
#else
  m = fmaxf(m, __int_as_float(
                   __builtin_amdgcn_ds_swizzle(__float_as_int(m), 0x401F)));
#endif
#if defined(HAVE_PL32)
  {
    auto r = __builtin_amdgcn_permlane32_swap(__float_as_int(m),
                                              __float_as_int(m), false, false);
    m = fmaxf(__int_as_float(r[0]), __int_as_float(r[1]));  // global max
  }
#else
  m = fmaxf(m, __int_as_float(__builtin_amdgcn_ds_bpermute(
                   ((lane ^ 32) << 2), __float_as_int(m))));
#endif
  return m;
}

// one block per pattern p: W2[p,0..31] + bias2[p]
__global__ __launch_bounds__(256) void precompute_kernel(
    const float* __restrict__ conv_w, const float* __restrict__ conv_b,
    const float* __restrict__ keys_w, float* __restrict__ wsf) {
  __shared__ float part[8][32];
  __shared__ float bred[4];
  const int p = blockIdx.x;
  const int t = threadIdx.x;
  const int h = t & 31, g = t >> 5;
  const float* kwp = keys_w + (size_t)p * DIMc;

  float acc = 0.f;
#pragma unroll
  for (int dd = 0; dd < 32; ++dd) {
    int d = g * 32 + dd;
    acc = fmaf(kwp[d], conv_w[d * HIST + h], acc);
  }
  part[g][h] = acc;

  float bp = kwp[t] * conv_b[t];
#pragma unroll
  for (int off = 32; off; off >>= 1) bp += __shfl_down(bp, off);
  if ((t & 63) == 0) bred[t >> 6] = bp;
  __syncthreads();

  if (t < 32) {
    float s = 0.f;
#pragma unroll
    for (int gg = 0; gg < 8; ++gg) s += part[gg][t];
    wsf[(t >> 2) * (NPAT * 4) + p * 4 + (t & 3)] = s;  // float4-friendly
  } else if (t == 32) {
    wsf[NPAT * HIST + p] = (bred[0] + bred[1]) + (bred[2] + bred[3]);
  }
}

__global__ __launch_bounds__(256) void shaper_kernel(
    const float* __restrict__ x, const float* __restrict__ avg_init,
    const float* __restrict__ shapes_w, const float* __restrict__ wsf,
    float* __restrict__ out) {
  __shared__ __align__(16) float xpad[HIST - 1 + Ll + 1];
  __shared__ float scb[2][TC * NPAT];
  __shared__ unsigned int bmbuf[2][64];   // per-lane win masks, dbuf
  __shared__ unsigned char idx8[Tt];      // winner pattern per step
  __shared__ float shp[WINc * NPAT];

  const int b    = blockIdx.x;
  const int tid  = threadIdx.x;
  const int wid  = tid >> 6;
  const int lane = tid & 63;
  const float* xrow = x + (size_t)b * Ll;

  // ---- stage x (left-padded) + shapes into LDS (all waves) ----
  if (tid < HIST - 1) xpad[tid] = 0.f;
  {
    const float4* xv4 = (const float4*)xrow;
#pragma unroll
    for (int k = 0; k < 8; ++k) {
      int i4 = k * 256 + tid;
      float4 v = xv4[i4];
      float* dst = xpad + HIST - 1 + i4 * 4;
      dst[0] = v.x; dst[1] = v.y; dst[2] = v.z; dst[3] = v.w;
    }
  }
  for (int i = tid; i < WINc * NPAT; i += 256) shp[i] = shapes_w[i];

  // ---- av0 via DPP-sum butterfly (all waves; validated R5/R8/R10) ----
  float av0;
  {
    float s = avg_init[(size_t)b * NPAT + lane];
    float t = s;
    DPP_ADDF(t, 0xB1, 0xF);
    DPP_ADDF(t, 0x4E, 0xF);
    DPP_ADDF(t, 0x141, 0xF);
    DPP_ADDF(t, 0x140, 0xF);
    DPP_ADDF(t, 0x142, 0xA);
    DPP_ADDF(t, 0x143, 0xC);   // lane63 = total
    float tot = __int_as_float(__builtin_amdgcn_readlane(__float_as_int(t), 63));
    av0 = s - tot * CINV;
  }

  __syncthreads();  // S1: staging complete (both paths)

  constexpr float SC75 = 37778931862957161709568.0f;  // 2^75

  if (wid == 0) {
    // =====================================================================
    // SCAN PATH (wave 0 only). No w2v here -> U[32] gets the registers.
    // =====================================================================
    float C = 0.f;
    __syncthreads();  // S2: fill(0) done

    for (int c = 0; c < NC; ++c) {
      const float* sb = scb[c & 1];
      float U[TC];
#pragma unroll
      for (int i = 0; i < TC; ++i) U[i] = sb[i * NPAT + lane];
      float bmlo = 0.f, bmhi = 0.f;
      float v  = U[0] - C;
      float pA = U[1] - C;
#pragma unroll
      for (int i = 0; i < TC; ++i) {
        float g  = wave_max64(v, lane);
        float d  = g - v;                            // +0 iff winner (exact)
        float t2 = __builtin_fmaf(d * SC75, -SC75, 1.0f);
        float e  = clamp01(t2);                      // == (v==g) ? 1 : 0
        C += e;                                      // integer-exact
        if (i < 16) bmlo = __builtin_fmaf(e, (float)(1u << i), bmlo);
        else        bmhi = __builtin_fmaf(e, (float)(1u << (i - 16)), bmhi);
        if (i + 1 < TC) {
          v = pA - e;                                // == e ? vA-1 : vA
          if (i + 2 < TC) pA = U[i + 2] - C;
        }
      }
      bmbuf[c & 1][lane] = (unsigned int)bmlo | ((unsigned int)bmhi << 16);
      __syncthreads();  // S3..S34
    }
    __syncthreads();  // S35: final extract done
  } else {
    // =====================================================================
    // FILL + EXTRACT PATH (waves 1-3). No U here -> w2v gets the registers.
    // =====================================================================
    float4 w2v[8];
    {
      const float4* w2g = (const float4*)wsf;
#pragma unroll
      for (int h4 = 0; h4 < 8; ++h4) w2v[h4] = w2g[h4 * 64 + lane];
    }
    float b2 = wsf[NPAT * HIST + lane];

    // fill chunk c (bitwise-identical to R12-R17; do not touch fma order)
    auto fill = [&](int c, float* __restrict__ sb) {
      int base = c * TC;
      for (int tl = wid - 1; tl < TC; tl += 3) {
        int t = base + tl;
        const float4* xw = (const float4*)(xpad + t * WINc);  // 32B-aligned
        float acc = b2;
#pragma unroll
        for (int h4 = 0; h4 < 8; ++h4) {
          float4 xv = xw[h4];
          float4 wv = w2v[h4];
          acc = fmaf(xv.x, wv.x, acc);
          acc = fmaf(xv.y, wv.y, acc);
          acc = fmaf(xv.z, wv.z, acc);
          acc = fmaf(xv.w, wv.w, acc);
        }
        float sc = fminf(fmaxf(acc, 0.f), 6.f);
        sb[tl * NPAT + lane] = (sc - av0) + (float)t * CINV;
      }
    };

    // batched winner extraction for chunk cc, split across waves 1-3
    // (R15-validated byte path; pattern == lane here)
    auto extract3 = [&](int cc) {
      unsigned int mv = bmbuf[cc & 1][lane];
      for (int i = wid - 1; i < TC; i += 3) {
        unsigned long long mk = __ballot(((mv >> i) & 1u) != 0u);
        int w = (int)(__ffsll(mk) - 1);
        if (lane == 0) idx8[cc * TC + i] = (unsigned char)w;
      }
    };

    fill(0, scb[0]);
    __syncthreads();  // S2

    for (int c = 0; c < NC; ++c) {
      if (c + 1 < NC) fill(c + 1, scb[(c + 1) & 1]);
      if (c >= 1) extract3(c - 1);
      __syncthreads();  // S3..S34
    }
    extract3(NC - 1);
    __syncthreads();  // S35
  }

  // ---- epilogue: out[b,l] = relu(shapes[l&7, idx[l>>3]] - x[b,l]) ----
  float4* outv = (float4*)(out + (size_t)b * Ll);
#pragma unroll
  for (int k = 0; k < 8; ++k) {
    int i4 = k * 256 + tid;
    int l0 = i4 * 4;
    int t  = l0 >> 3;
    int w0 = l0 & 7;
    int p  = (int)idx8[t];
    float4 o;
    o.x = fmaxf(shp[(w0 + 0) * NPAT + p] - xpad[HIST - 1 + l0 + 0], 0.f);
    o.y = fmaxf(shp[(w0 + 1) * NPAT + p] - xpad[HIST - 1 + l0 + 1], 0.f);
    o.z = fmaxf(shp[(w0 + 2) * NPAT + p] - xpad[HIST - 1 + l0 + 2], 0.f);
    o.w = fmaxf(shp[(w0 + 3) * NPAT + p] - xpad[HIST - 1 + l0 + 3], 0.f);
    outv[i4] = o;
  }
}

extern "C" void kernel_launch(void* const* d_in, const int* in_sizes, int n_in,
                              void* d_out, int out_size, void* d_ws, size_t ws_size,
                              hipStream_t stream) {
  const float* x        = (const float*)d_in[0];
  const float* avg_init = (const float*)d_in[1];
  const float* conv_w   = (const float*)d_in[2];
  const float* conv_b   = (const float*)d_in[3];
  const float* keys_w   = (const float*)d_in[4];
  const float* shapes_w = (const float*)d_in[5];
  float* wsf = (float*)d_ws;

  precompute_kernel<<<NPAT, 256, 0, stream>>>(conv_w, conv_b, keys_w, wsf);
  shaper_kernel<<<Bb, 256, 0, stream>>>(x, avg_init, shapes_w, wsf,
                                        (float*)d_out);
}